// Round 3
// 8666.406 us; speedup vs baseline: 1.1341x; 1.1341x over previous
//
#include <hip/hip_runtime.h>
#include <hip/hip_cooperative_groups.h>

// x: [B=256, T=100, D=4096] f32; Z: [H=1024, D=4096] f32; KFinv: [D, H] f32
// out[:,t,:] = sigmoid((x_t - nb_{t-1}) @ KFinv + b_h) @ Z + b_out), nb_{-1}=b_out
#define T_SEQ 100
#define DD 4096
#define HH 1024
#define BB 256

#define GRID_WG 256   // == CU count: cooperative launch safe at 1 block/CU
#define BLOCK_T 512   // 8 waves

typedef __attribute__((ext_vector_type(8))) short short8;
typedef __attribute__((ext_vector_type(4))) float float4_t;

__device__ __forceinline__ short f2bf(float f) {
  union { float f; unsigned u; } v; v.f = f;
  unsigned r = v.u + 0x7fffu + ((v.u >> 16) & 1u);  // RNE
  return (short)(r >> 16);
}

// LDS XOR swizzle (units: shorts). Bijective within a row; same formula on
// write and read. Spreads the 16-row b128 read across 8 bank-groups.
__device__ __forceinline__ int swz(int row, int col) {
  return col ^ ((row & 7) << 3);
}

// one-time prep: f32 [K][N] -> bf16 [N][K]
__global__ __launch_bounds__(256) void transpose_cvt(const float* __restrict__ src,
                                                     short* __restrict__ dst,
                                                     int K, int N) {
  __shared__ float tile[32][33];
  int k0 = blockIdx.x * 32, n0 = blockIdx.y * 32;
  int tx = threadIdx.x & 31, ty = threadIdx.x >> 5;  // 32 x 8
#pragma unroll
  for (int i = 0; i < 32; i += 8)
    tile[ty + i][tx] = src[(size_t)(k0 + ty + i) * N + n0 + tx];
  __syncthreads();
#pragma unroll
  for (int i = 0; i < 32; i += 8)
    dst[(size_t)(n0 + ty + i) * K + k0 + tx] = f2bf(tile[tx][ty + i]);
}

__global__ __launch_bounds__(BLOCK_T, 2) void gru_persist(
    const float* __restrict__ x, const short* __restrict__ KFt /*[H][D] bf16*/,
    const short* __restrict__ Zt /*[D][H] bf16*/, const float* __restrict__ b_out,
    const float* __restrict__ b_hidden, short* __restrict__ diff /*[B][D] bf16*/,
    short* __restrict__ hb /*[B][H] bf16*/, float* __restrict__ out) {
  // [dbuf][panel A/B][16 KiB of shorts] = 64 KiB total (same budget class as
  // the verified round-0 kernel; phase A views panels as [32][256], phase B
  // as [64][128], both swizzled).
  __shared__ short smem[2][2][8192];
  auto grid = cooperative_groups::this_grid();

  const int g = blockIdx.x, tid = threadIdx.x;
  const int lane = tid & 63, wid = tid >> 6;
  const int quad = lane >> 4, l15 = lane & 15;
  const int gsize = GRID_WG * BLOCK_T;
  const int gtid = g * BLOCK_T + tid;

  // ---- init: diff_0 = x[:,0,:] - b_out (packed u32 plain stores)
  for (int idx = gtid; idx < BB * DD / 2; idx += gsize) {
    int m = idx >> 11, d = (idx & 2047) * 2;
    const float* xp = &x[(size_t)m * T_SEQ * DD + d];
    unsigned lo = (unsigned short)f2bf(xp[0] - b_out[d]);
    unsigned hi = (unsigned short)f2bf(xp[1] - b_out[d + 1]);
    ((unsigned*)diff)[idx] = lo | (hi << 16);
  }

  // Phase A mapping: XCD x handles nA slices {4x..4x+3}; 8 m-tiles x 4 n per XCD.
  const int xcd = g & 7, loc = g >> 3;
  const int maA = (loc & 7) * 32;               // m base (tile 32)
  const int naA = (4 * xcd + (loc >> 3)) * 32;  // n base (tile 32)
  const int wkA = wid >> 2, wqA = wid & 3;      // 2 k-halves x 4 quadrant waves
  const int wmA = wqA >> 1, wnA = wqA & 1;
  // Phase B mapping: XCD x handles nB slices {8x..8x+7}; 4 m-tiles x 8 n per XCD.
  const int maB = (loc & 3) * 64;               // m base (tile 64)
  const int naB = (8 * xcd + (loc >> 2)) * 64;  // n base (tile 64)
  const int wmB = wid >> 1, wnB = wid & 1;      // 4 x 2 waves over 64x64
  // staging coords
  const int srA = tid >> 4, scA = tid & 15;  // 32 rows x 16 col-threads
  const int srB = tid >> 3, scB = tid & 7;   // 64 rows x 8 col-threads

  short8 wK[2], wD[2], wZ[2], wH[2];

  // prefetch KFt chunk 0 (immutable -> safe to issue before the barrier)
#pragma unroll
  for (int j = 0; j < 2; ++j)
    wK[j] = *(const short8*)&KFt[(size_t)(naA + srA) * DD + scA * 8 + j * 128];

  grid.sync();

  for (int t = 0; t < T_SEQ; ++t) {
    // ============ Phase A: hb = diff @ KFinv + b_hidden  (tile 32x32, K=4096)
    {
      float4_t acc = {0.f, 0.f, 0.f, 0.f};
#pragma unroll
      for (int j = 0; j < 2; ++j)
        wD[j] = *(const short8*)&diff[(size_t)(maA + srA) * DD + scA * 8 + j * 128];
#pragma unroll
      for (int j = 0; j < 2; ++j) {
        int co = swz(srA, scA * 8 + j * 128);
        *(short8*)&smem[0][0][srA * 256 + co] = wD[j];
        *(short8*)&smem[0][1][srA * 256 + co] = wK[j];
      }
      int cur = 0;
      const int arow = wmA * 16 + l15, brow = wnA * 16 + l15;
      const int ko = wkA * 128;
#pragma unroll 1
      for (int it = 0; it < 16; ++it) {  // K chunks of 256
        __syncthreads();
        if (it < 15) {  // prefetch next chunk while this one computes
          const int kb = (it + 1) * 256;
#pragma unroll
          for (int j = 0; j < 2; ++j) {
            wD[j] = *(const short8*)&diff[(size_t)(maA + srA) * DD + kb + scA * 8 + j * 128];
            wK[j] = *(const short8*)&KFt[(size_t)(naA + srA) * DD + kb + scA * 8 + j * 128];
          }
        }
        const short* sA = smem[cur][0];
        const short* sB = smem[cur][1];
#pragma unroll
        for (int ks = 0; ks < 4; ++ks) {
          short8 a = *(const short8*)&sA[arow * 256 + swz(arow, ko + ks * 32 + quad * 8)];
          short8 b = *(const short8*)&sB[brow * 256 + swz(brow, ko + ks * 32 + quad * 8)];
          acc = __builtin_amdgcn_mfma_f32_16x16x32_bf16(a, b, acc, 0, 0, 0);
        }
        if (it < 15) {
          cur ^= 1;
#pragma unroll
          for (int j = 0; j < 2; ++j) {
            int co = swz(srA, scA * 8 + j * 128);
            *(short8*)&smem[cur][0][srA * 256 + co] = wD[j];
            *(short8*)&smem[cur][1][srA * 256 + co] = wK[j];
          }
        }
      }
      // cross-k-half reduce through LDS, then exclusive-owner bf16 store
      __syncthreads();
      float* red = (float*)&smem[0][0][0];  // last compute buf was smem[1]
      if (wkA == 1) {
#pragma unroll
        for (int r = 0; r < 4; ++r) red[(wqA * 64 + lane) * 4 + r] = acc[r];
      }
      __syncthreads();
      if (wkA == 0) {
#pragma unroll
        for (int r = 0; r < 4; ++r) {
          float v = acc[r] + red[(wqA * 64 + lane) * 4 + r];
          int m = maA + wmA * 16 + quad * 4 + r;
          int n = naA + wnA * 16 + l15;
          float hv = v + b_hidden[n];
          float ov = __shfl_xor(hv, 1);
          if (!(lane & 1)) {
            unsigned w = (unsigned)(unsigned short)f2bf(hv) |
                         ((unsigned)(unsigned short)f2bf(ov) << 16);
            *(unsigned*)&hb[m * HH + n] = w;  // plain store; grid.sync publishes
          }
        }
      }
    }
    // prefetch Zt chunk 0 for phase B (immutable -> latency hides under barrier)
#pragma unroll
    for (int j = 0; j < 2; ++j)
      wZ[j] = *(const short8*)&Zt[(size_t)(naB + srB) * HH + scB * 8 + j * 64];
    grid.sync();

    // ============ Phase B: s = sigmoid(hb @ Z + b_out); out, diff_{t+1} =====
    {
      float4_t acc2[2] = {};
      float xr[8];
      if (t < T_SEQ - 1) {  // hoist x[t+1] loads: hide cold-HBM latency under GEMM
#pragma unroll
        for (int f = 0; f < 2; ++f)
#pragma unroll
          for (int r = 0; r < 4; ++r) {
            int m = maB + wmB * 16 + quad * 4 + r;
            int n = naB + wnB * 32 + f * 16 + l15;
            xr[f * 4 + r] = x[((size_t)m * T_SEQ + t + 1) * DD + n];
          }
      }
#pragma unroll
      for (int j = 0; j < 2; ++j)
        wH[j] = *(const short8*)&hb[(size_t)(maB + srB) * HH + scB * 8 + j * 64];
#pragma unroll
      for (int j = 0; j < 2; ++j) {
        int co = swz(srB, scB * 8 + j * 64);
        *(short8*)&smem[0][0][srB * 128 + co] = wH[j];
        *(short8*)&smem[0][1][srB * 128 + co] = wZ[j];
      }
      int cur = 0;
      const int arowB = wmB * 16 + l15;
      const int b0row = wnB * 32 + l15, b1row = wnB * 32 + 16 + l15;
#pragma unroll 1
      for (int it = 0; it < 8; ++it) {  // K chunks of 128 (K=1024)
        __syncthreads();
        if (it < 7) {
          const int kb = (it + 1) * 128;
#pragma unroll
          for (int j = 0; j < 2; ++j) {
            wH[j] = *(const short8*)&hb[(size_t)(maB + srB) * HH + kb + scB * 8 + j * 64];
            wZ[j] = *(const short8*)&Zt[(size_t)(naB + srB) * HH + kb + scB * 8 + j * 64];
          }
        }
        const short* sA = smem[cur][0];
        const short* sB = smem[cur][1];
#pragma unroll
        for (int ks = 0; ks < 4; ++ks) {
          short8 a  = *(const short8*)&sA[arowB * 128 + swz(arowB, ks * 32 + quad * 8)];
          short8 b0 = *(const short8*)&sB[b0row * 128 + swz(b0row, ks * 32 + quad * 8)];
          short8 b1 = *(const short8*)&sB[b1row * 128 + swz(b1row, ks * 32 + quad * 8)];
          acc2[0] = __builtin_amdgcn_mfma_f32_16x16x32_bf16(a, b0, acc2[0], 0, 0, 0);
          acc2[1] = __builtin_amdgcn_mfma_f32_16x16x32_bf16(a, b1, acc2[1], 0, 0, 0);
        }
        if (it < 7) {
          cur ^= 1;
#pragma unroll
          for (int j = 0; j < 2; ++j) {
            int co = swz(srB, scB * 8 + j * 64);
            *(short8*)&smem[cur][0][srB * 128 + co] = wH[j];
            *(short8*)&smem[cur][1][srB * 128 + co] = wZ[j];
          }
        }
      }
#pragma unroll
      for (int f = 0; f < 2; ++f)
#pragma unroll
        for (int r = 0; r < 4; ++r) {
          int m = maB + wmB * 16 + quad * 4 + r;
          int n = naB + wnB * 32 + f * 16 + l15;
          float z = acc2[f][r] + b_out[n];
          float s = 1.f / (1.f + __expf(-z));
          out[((size_t)m * T_SEQ + t) * DD + n] = s;
          if (t < T_SEQ - 1) {
            short db = f2bf(xr[f * 4 + r] - s);
            int ob = __shfl_xor((int)(unsigned short)db, 1);
            if (!(lane & 1)) {
              unsigned w = (unsigned)(unsigned short)db | ((unsigned)ob << 16);
              *(unsigned*)&diff[(size_t)m * DD + n] = w;  // plain store
            }
          }
        }
    }
    // prefetch next step's KFt chunk 0 (immutable)
    if (t < T_SEQ - 1) {
#pragma unroll
      for (int j = 0; j < 2; ++j)
        wK[j] = *(const short8*)&KFt[(size_t)(naA + srA) * DD + scA * 8 + j * 128];
    }
    grid.sync();
  }
}

extern "C" void kernel_launch(void* const* d_in, const int* in_sizes, int n_in,
                              void* d_out, int out_size, void* d_ws, size_t ws_size,
                              hipStream_t stream) {
  const float* x = (const float*)d_in[0];
  const float* Z = (const float*)d_in[1];
  const float* b_out = (const float*)d_in[2];
  const float* KFinv = (const float*)d_in[3];
  const float* b_hidden = (const float*)d_in[4];
  float* out = (float*)d_out;

  char* ws = (char*)d_ws;
  short* KFt = (short*)ws;                    // [1024][4096] bf16 : 8 MiB
  short* Zt = (short*)(ws + 8388608);         // [4096][1024] bf16 : 8 MiB
  short* diff = (short*)(ws + 16777216);      // [256][4096] bf16  : 2 MiB
  short* hb = (short*)(ws + 18874368);        // [256][1024] bf16  : 512 KiB

  transpose_cvt<<<dim3(128, 32), 256, 0, stream>>>(KFinv, KFt, 4096, 1024);
  transpose_cvt<<<dim3(32, 128), 256, 0, stream>>>(Z, Zt, 1024, 4096);

  void* args[] = {(void*)&x,        (void*)&KFt,  (void*)&Zt, (void*)&b_out,
                  (void*)&b_hidden, (void*)&diff, (void*)&hb, (void*)&out};
  hipLaunchCooperativeKernel((void*)gru_persist, dim3(GRID_WG), dim3(BLOCK_T), args, 0,
                             stream);
}